// Round 20
// baseline (177.750 us; speedup 1.0000x reference)
//
#include <hip/hip_runtime.h>
#include <hip/hip_bf16.h>

// LS2T iterated sums (ORDER=3): B=64, T=4096, D=128, F=64, C=6.
// m_c(t,f) = seq[b,t,:]·kernel[c,:,f] + bias[c,f]
// Y1 = sum m0; Y2 = sum m2*cumx(m1); Y3 = sum m5*cumx(m4*cumx(m3))
//
// Round 20: R15 byte-identical (grid (8,64), 512 thr, in-block cg split,
// CHT=32 ring-4 DMA pipeline, counted vmcnt, verified swizzle pair) + fused
// fold appended: release fence -> atomicAdd(cnt[b]) -> 8th block of batch b
// acquire-fences and folds the 8 span-states (tg ascending) into out.
// Second launch and its gap eliminated. cnt zeroed per call via
// hipMemsetAsync (graph-safe, deterministic).

#define B_ 64
#define T_ 4096
#define D_ 128
#define F_ 64
#define TB 512             // t per block
#define TGROUPS (T_ / TB)  // 8
#define CHT 32             // t per chunk (2 MFMA sub-tiles)
#define NITER (TB / CHT)   // 16
#define TPB 512
#define RING 4
#define WS_STATES ((size_t)B_ * TGROUPS * F_ * 10)   // floats

typedef __attribute__((ext_vector_type(8))) short short8v;
typedef __attribute__((ext_vector_type(4))) float f32x4;

__device__ __forceinline__ unsigned short bfb(float x) {
    __hip_bfloat16 h = __float2bfloat16(x);   // RNE (B operand only)
    unsigned short u;
    __builtin_memcpy(&u, &h, 2);
    return u;
}

// barrier WITHOUT vmcnt drain: waits only LDS ops, keeps DMAs in flight
#define BAR() asm volatile("s_waitcnt lgkmcnt(0)\n\ts_barrier" ::: "memory")
#define VW(n) asm volatile("s_waitcnt vmcnt(" #n ")" ::: "memory")

struct St { float a0, s1, s2, q2, su, sv, sw, qvu, qwv, qwvu; };

__device__ __forceinline__ St mergeSt(const St& A, const St& B) {
    St r;
    r.a0   = A.a0 + B.a0;
    r.q2   = A.q2 + B.q2 + A.s1 * B.s2;
    r.s1   = A.s1 + B.s1;
    r.s2   = A.s2 + B.s2;
    r.qwvu = A.qwvu + B.qwvu + A.qvu * B.sw + A.su * B.qwv;
    r.qwv  = A.qwv + B.qwv + A.sv * B.sw;
    r.qvu  = A.qvu + B.qvu + A.su * B.sv;
    r.su   = A.su + B.su;
    r.sv   = A.sv + B.sv;
    r.sw   = A.sw + B.sw;
    return r;
}

__global__ __launch_bounds__(TPB)
void ls2t_kernel(const float* __restrict__ seq,
                 const float* __restrict__ kern,
                 const float* __restrict__ bias,
                 float* ws,
                 int* cnt,
                 float* __restrict__ out)
{
    __shared__ float slds[RING][CHT * D_];   // 4 x 16 KB f32

    const int tid  = threadIdx.x;
    const int tg   = blockIdx.x;             // 0..7 (R15 grid)
    const int b    = blockIdx.y;
    const int lane = tid & 63;
    const int w    = tid >> 6;
    const int cg   = w >> 2;       // 0 -> c0..2 (Y1,Y2), 1 -> c3..5 (Y3)
    const int wv   = w & 3;        // f-range of this wave
    const int fr   = lane & 15;
    const int lg   = lane >> 4;
    const int f    = wv * 16 + fr;

    // ---- B fragments in registers (mfma B: col=lane&15=f, k=(lane>>4)*8+j)
    short8v bfrag[3][4];
    float bc[3];
    #pragma unroll
    for (int cc = 0; cc < 3; ++cc) {
        const int c = cg * 3 + cc;
        bc[cc] = bias[c * F_ + f];
        #pragma unroll
        for (int ks = 0; ks < 4; ++ks) {
            const float* kp = kern + ((size_t)c * D_ + ks * 32 + lg * 8) * F_ + f;
            short8v bf;
            #pragma unroll
            for (int j = 0; j < 8; ++j) bf[j] = (short)bfb(kp[(size_t)j * F_]);
            bfrag[cc][ks] = bf;
        }
    }

    const float* sbase = seq + ((size_t)b * T_ + (size_t)tg * TB) * D_;

    // ---- DMA staging geometry (R15 exact) ----
    // Chunk = 32 rows. Row R (0..31) of chunk i holds
    //   t_local = ((R&15)>>2)*128 + ((R>>4)<<2) + (R&3) + i*8
    // (sub-tile tf=R>>4, MFMA row rho=R&15; lane-group lg owns contiguous
    // t-stripe [lg*128,+128) over the 16 chunks). Wave w stages rows
    // {4w..4w+3} via 2 loads; dest linear (base + lane*16B). Pre-swizzled
    // SOURCE: LDS 16B-unit u of row R holds global unit (u&24)|((u^R)&7).
    const int u_lane = lane & 31;
    const float* gsrc0[2];
    #pragma unroll
    for (int j = 0; j < 2; ++j) {
        const int r  = 4 * w + 2 * j + (lane >> 5);
        const int gu = (u_lane & 24) | ((u_lane ^ r) & 7);
        const int t0 = ((r & 15) >> 2) * 128 + ((r >> 4) << 2) + (r & 3);
        gsrc0[j] = sbase + (size_t)t0 * D_ + gu * 4;
    }

    auto issue = [&](int i, int bufi) {
        #pragma unroll
        for (int j = 0; j < 2; ++j) {
            const float* src = gsrc0[j] + (size_t)i * 8 * D_;
            void* dst = (void*)&slds[bufi][(4 * w + 2 * j) * 128];
            __builtin_amdgcn_global_load_lds(
                (const __attribute__((address_space(1))) void*)src,
                (__attribute__((address_space(3))) void*)dst, 16, 0, 0);
        }
    };

    // unified scan state (cg0: a0=x0,s1=x1,s2=x2,q2=x4; cg1: su..qwvu=x0..x5)
    float x0 = 0.f, x1 = 0.f, x2 = 0.f, x3 = 0.f, x4 = 0.f, x5 = 0.f;

    auto compute = [&](int bufi) {
        const float* L = &slds[bufi][0];
        #pragma unroll
        for (int tf = 0; tf < 2; ++tf) {       // two 16x16 sub-tiles
            f32x4 acc[3];
            #pragma unroll
            for (int cc = 0; cc < 3; ++cc)
                acc[cc] = (f32x4){bc[cc], bc[cc], bc[cc], bc[cc]};

            const int rowbase = (tf * 16 + fr) * 128;
            #pragma unroll
            for (int ks = 0; ks < 4; ++ks) {
                const int u0  = ks * 8 + lg * 2;
                const int s0  = (u0 & 24) | ((u0 ^ fr) & 7);
                const int s1u = ((u0 + 1) & 24) | (((u0 + 1) ^ fr) & 7);
                float4 fa = *reinterpret_cast<const float4*>(&L[rowbase + s0 * 4]);
                float4 fb = *reinterpret_cast<const float4*>(&L[rowbase + s1u * 4]);
                uint4 pk;
                pk.x = __builtin_amdgcn_perm(__float_as_uint(fa.y),
                                             __float_as_uint(fa.x), 0x07060302u);
                pk.y = __builtin_amdgcn_perm(__float_as_uint(fa.w),
                                             __float_as_uint(fa.z), 0x07060302u);
                pk.z = __builtin_amdgcn_perm(__float_as_uint(fb.y),
                                             __float_as_uint(fb.x), 0x07060302u);
                pk.w = __builtin_amdgcn_perm(__float_as_uint(fb.w),
                                             __float_as_uint(fb.z), 0x07060302u);
                short8v a = *reinterpret_cast<short8v*>(&pk);
                #pragma unroll
                for (int cc = 0; cc < 3; ++cc)
                    acc[cc] = __builtin_amdgcn_mfma_f32_16x16x32_bf16(
                        a, bfrag[cc][ks], acc[cc], 0, 0, 0);
            }

            // lane owns t = tg*512 + lg*128 + i*8 + tf*4 + r -> chain in-lane
            #pragma unroll
            for (int r = 0; r < 4; ++r) {
                float p = acc[0][r], q = acc[1][r], rr = acc[2][r];
                x5 = fmaf(rr, x3, x5);   // qwvu += m5*qvu            (cg1)
                x4 = fmaf(rr, x1, x4);   // q2 += m2*s1 / qwv += m5*sv
                x3 = fmaf(q,  x0, x3);   // qvu += m4*su              (cg1)
                x2 += rr;                // s2 / sw
                x1 += q;                 // s1 / sv
                x0 += p;                 // a0 / su
            }
        }
    };

    // ---- pipeline: DMA 3 chunks ahead (2 loads each), counted vmcnt ----
    issue(0, 0); issue(1, 1); issue(2, 2);

    #pragma unroll 1
    for (int i = 0; i < NITER - 3; ++i) {
        VW(4);                 // own chunk-i loads landed (4 newer in flight)
        BAR();                 // => all waves' chunk-i rows landed
        issue(i + 3, (i + 3) & 3);
        compute(i & 3);
    }
    VW(4); BAR(); compute(1);
    VW(2); BAR(); compute(2);
    VW(0); BAR(); compute(3);

    // ---- merge the 4 lane-group stripes (time order: lg ascending) ----
    #pragma unroll
    for (int m = 16; m <= 32; m <<= 1) {
        float o0 = __shfl_xor(x0, m), o1 = __shfl_xor(x1, m);
        float o2 = __shfl_xor(x2, m), o3 = __shfl_xor(x3, m);
        float o4 = __shfl_xor(x4, m), o5 = __shfl_xor(x5, m);
        const bool up = (lane & m) != 0;   // this lane holds the LATER segment
        float A0 = up ? o0 : x0, B0 = up ? x0 : o0;
        float A1 = up ? o1 : x1, B1 = up ? x1 : o1;
        float A2 = up ? o2 : x2, B2 = up ? x2 : o2;
        float A3 = up ? o3 : x3, B3 = up ? x3 : o3;
        float A4 = up ? o4 : x4, B4 = up ? x4 : o4;
        float A5 = up ? o5 : x5, B5 = up ? x5 : o5;
        x5 = A5 + B5 + A3 * B2 + A0 * B4;
        x4 = A4 + B4 + A1 * B2;
        x3 = A3 + B3 + A0 * B1;
        x2 = A2 + B2;
        x1 = A1 + B1;
        x0 = A0 + B0;
    }

    if (lg == 0) {
        float* wp = ws + (((size_t)b * TGROUPS + tg) * F_ + f) * 10;
        if (cg == 0) {
            wp[0] = x0; wp[1] = x1; wp[2] = x2; wp[3] = x4;
        } else {
            wp[4] = x0; wp[5] = x1; wp[6] = x2;
            wp[7] = x3; wp[8] = x4; wp[9] = x5;
        }
    }

    // ---- fused fold: 8th-arriving block of batch b folds its 8 states ----
    __threadfence();            // release: ws writes device-visible
    __syncthreads();            // all lanes' fences done before the signal
    __shared__ int amLast;
    if (tid == 0) amLast = (atomicAdd(&cnt[b], 1) == TGROUPS - 1);
    __syncthreads();
    if (amLast) {
        __threadfence();        // acquire: all 8 blocks' states visible
        if (tid < F_) {
            const int ff = tid;
            St A = {0, 0, 0, 0, 0, 0, 0, 0, 0, 0};
            #pragma unroll
            for (int g = 0; g < TGROUPS; ++g) {
                const float* rp = ws + (((size_t)b * TGROUPS + g) * F_ + ff) * 10;
                St r = {rp[0], rp[1], rp[2], rp[3], rp[4],
                        rp[5], rp[6], rp[7], rp[8], rp[9]};
                A = mergeSt(A, r);
            }
            float* op = out + ((size_t)b * F_ + ff) * 3;
            op[0] = A.a0;
            op[1] = A.q2;
            op[2] = A.qwvu;
        }
    }
}

extern "C" void kernel_launch(void* const* d_in, const int* in_sizes, int n_in,
                              void* d_out, int out_size, void* d_ws, size_t ws_size,
                              hipStream_t stream) {
    const float* seq  = (const float*)d_in[0];
    const float* kern = (const float*)d_in[1];
    const float* bias = (const float*)d_in[2];
    float* out = (float*)d_out;
    float* ws  = (float*)d_ws;                 // states: 1.31 MB
    int*   cnt = (int*)(ws + WS_STATES);       // 64 ints after the states

    hipMemsetAsync(cnt, 0, B_ * sizeof(int), stream);   // graph-capture-safe
    dim3 g1(TGROUPS, B_);        // 512 blocks x 512 thr (R15 grid)
    ls2t_kernel<<<g1, TPB, 0, stream>>>(seq, kern, bias, ws, cnt, out);
}

// Round 21
// 41.550 us; speedup vs baseline: 4.2779x; 4.2779x over previous
//
#include <hip/hip_runtime.h>
#include <hip/hip_bf16.h>

// LS2T iterated sums (ORDER=3): B=64, T=4096, D=128, F=64, C=6.
// m_c(t,f) = seq[b,t,:]·kernel[c,:,f] + bias[c,f]
// Y1 = sum m0; Y2 = sum m2*cumx(m1); Y3 = sum m5*cumx(m4*cumx(m3))
//
// Round 21: R15 (best, 41.1us) with ONE variable: RING 4->3 (48 KB LDS) ->
// 3 blocks/CU resident (was 2), +50% waves to overlap barrier/drain bubbles.
// Prefetch depth 3->2 chunks, vmcnt(2): phase wall-time (~4.7us) >> HBM
// latency so depth-2 still covers fully. Two-kernel structure restored
// (R20's fence-based fusion invalidated L2 chip-wide: 4x regression).
// Same grid (8,64), 512 thr, in-block cg split, verified swizzle pair,
// unified 6-reg scan, butterfly merge, separate fold kernel.

#define B_ 64
#define T_ 4096
#define D_ 128
#define F_ 64
#define TB 512             // t per block
#define TGROUPS (T_ / TB)  // 8
#define CHT 32             // t per chunk (2 MFMA sub-tiles)
#define NITER (TB / CHT)   // 16
#define TPB 512
#define RING 3

typedef __attribute__((ext_vector_type(8))) short short8v;
typedef __attribute__((ext_vector_type(4))) float f32x4;

__device__ __forceinline__ unsigned short bfb(float x) {
    __hip_bfloat16 h = __float2bfloat16(x);   // RNE (B operand only)
    unsigned short u;
    __builtin_memcpy(&u, &h, 2);
    return u;
}

// barrier WITHOUT vmcnt drain: waits only LDS ops, keeps DMAs in flight
#define BAR() asm volatile("s_waitcnt lgkmcnt(0)\n\ts_barrier" ::: "memory")
#define VW(n) asm volatile("s_waitcnt vmcnt(" #n ")" ::: "memory")

__global__ __launch_bounds__(TPB)
void ls2t_kernel(const float* __restrict__ seq,
                 const float* __restrict__ kern,
                 const float* __restrict__ bias,
                 float* __restrict__ ws)
{
    __shared__ float slds[RING][CHT * D_];   // 3 x 16 KB f32

    const int tid  = threadIdx.x;
    const int tg   = blockIdx.x;
    const int b    = blockIdx.y;
    const int lane = tid & 63;
    const int w    = tid >> 6;
    const int cg   = w >> 2;       // 0 -> c0..2 (Y1,Y2), 1 -> c3..5 (Y3)
    const int wv   = w & 3;        // f-range of this wave
    const int fr   = lane & 15;
    const int lg   = lane >> 4;
    const int f    = wv * 16 + fr;

    // ---- B fragments in registers (mfma B: col=lane&15=f, k=(lane>>4)*8+j)
    short8v bfrag[3][4];
    float bc[3];
    #pragma unroll
    for (int cc = 0; cc < 3; ++cc) {
        const int c = cg * 3 + cc;
        bc[cc] = bias[c * F_ + f];
        #pragma unroll
        for (int ks = 0; ks < 4; ++ks) {
            const float* kp = kern + ((size_t)c * D_ + ks * 32 + lg * 8) * F_ + f;
            short8v bf;
            #pragma unroll
            for (int j = 0; j < 8; ++j) bf[j] = (short)bfb(kp[(size_t)j * F_]);
            bfrag[cc][ks] = bf;
        }
    }

    const float* sbase = seq + ((size_t)b * T_ + (size_t)tg * TB) * D_;

    // ---- DMA staging geometry (R15 exact) ----
    // Chunk = 32 rows. Row R (0..31) of chunk i holds
    //   t_local = ((R&15)>>2)*128 + ((R>>4)<<2) + (R&3) + i*8
    // (sub-tile tf=R>>4, MFMA row rho=R&15; lane-group lg owns contiguous
    // t-stripe [lg*128,+128) over the 16 chunks). Wave w stages rows
    // {4w..4w+3} via 2 loads (load j covers rows 4w+2j+(lane>>5)); dest
    // linear (base + lane*16B). Pre-swizzled SOURCE: LDS 16B-unit u of row R
    // holds global unit (u&24) | ((u^R)&7).
    const int u_lane = lane & 31;
    const float* gsrc0[2];
    #pragma unroll
    for (int j = 0; j < 2; ++j) {
        const int r  = 4 * w + 2 * j + (lane >> 5);
        const int gu = (u_lane & 24) | ((u_lane ^ r) & 7);
        const int t0 = ((r & 15) >> 2) * 128 + ((r >> 4) << 2) + (r & 3);
        gsrc0[j] = sbase + (size_t)t0 * D_ + gu * 4;
    }

    auto issue = [&](int i, int bufi) {
        #pragma unroll
        for (int j = 0; j < 2; ++j) {
            const float* src = gsrc0[j] + (size_t)i * 8 * D_;
            void* dst = (void*)&slds[bufi][(4 * w + 2 * j) * 128];
            __builtin_amdgcn_global_load_lds(
                (const __attribute__((address_space(1))) void*)src,
                (__attribute__((address_space(3))) void*)dst, 16, 0, 0);
        }
    };

    // unified scan state (cg0: a0=x0,s1=x1,s2=x2,q2=x4; cg1: su..qwvu=x0..x5)
    float x0 = 0.f, x1 = 0.f, x2 = 0.f, x3 = 0.f, x4 = 0.f, x5 = 0.f;

    auto compute = [&](int bufi) {
        const float* L = &slds[bufi][0];
        #pragma unroll
        for (int tf = 0; tf < 2; ++tf) {       // two 16x16 sub-tiles
            f32x4 acc[3];
            #pragma unroll
            for (int cc = 0; cc < 3; ++cc)
                acc[cc] = (f32x4){bc[cc], bc[cc], bc[cc], bc[cc]};

            const int rowbase = (tf * 16 + fr) * 128;
            #pragma unroll
            for (int ks = 0; ks < 4; ++ks) {
                const int u0  = ks * 8 + lg * 2;
                const int s0  = (u0 & 24) | ((u0 ^ fr) & 7);
                const int s1u = ((u0 + 1) & 24) | (((u0 + 1) ^ fr) & 7);
                float4 fa = *reinterpret_cast<const float4*>(&L[rowbase + s0 * 4]);
                float4 fb = *reinterpret_cast<const float4*>(&L[rowbase + s1u * 4]);
                uint4 pk;
                pk.x = __builtin_amdgcn_perm(__float_as_uint(fa.y),
                                             __float_as_uint(fa.x), 0x07060302u);
                pk.y = __builtin_amdgcn_perm(__float_as_uint(fa.w),
                                             __float_as_uint(fa.z), 0x07060302u);
                pk.z = __builtin_amdgcn_perm(__float_as_uint(fb.y),
                                             __float_as_uint(fb.x), 0x07060302u);
                pk.w = __builtin_amdgcn_perm(__float_as_uint(fb.w),
                                             __float_as_uint(fb.z), 0x07060302u);
                short8v a = *reinterpret_cast<short8v*>(&pk);
                #pragma unroll
                for (int cc = 0; cc < 3; ++cc)
                    acc[cc] = __builtin_amdgcn_mfma_f32_16x16x32_bf16(
                        a, bfrag[cc][ks], acc[cc], 0, 0, 0);
            }

            // lane owns t = tg*512 + lg*128 + i*8 + tf*4 + r -> chain in-lane
            #pragma unroll
            for (int r = 0; r < 4; ++r) {
                float p = acc[0][r], q = acc[1][r], rr = acc[2][r];
                x5 = fmaf(rr, x3, x5);   // qwvu += m5*qvu            (cg1)
                x4 = fmaf(rr, x1, x4);   // q2 += m2*s1 / qwv += m5*sv
                x3 = fmaf(q,  x0, x3);   // qvu += m4*su              (cg1)
                x2 += rr;                // s2 / sw
                x1 += q;                 // s1 / sv
                x0 += p;                 // a0 / su
            }
        }
    };

    // ---- pipeline: DMA 2 chunks ahead, ring-3, counted vmcnt(2) ----
    issue(0, 0); issue(1, 1);

    int b0 = 0, b1 = 1, b2 = 2;
    #pragma unroll 1
    for (int i = 0; i < NITER - 2; ++i) {
        VW(2);                 // own chunk-i loads landed (chunk i+1 in flight)
        BAR();                 // => all waves' chunk-i rows landed; also: all
                               //    waves finished compute(i-1) -> buf b2 free
        issue(i + 2, b2);
        compute(b0);
        int t = b0; b0 = b1; b1 = b2; b2 = t;
    }
    // tail: chunks 14,15 (outstanding loads drain 2 -> 0)
    VW(2); BAR(); compute(b0);
    VW(0); BAR(); compute(b1);

    // ---- merge the 4 lane-group stripes (time order: lg ascending) ----
    #pragma unroll
    for (int m = 16; m <= 32; m <<= 1) {
        float o0 = __shfl_xor(x0, m), o1 = __shfl_xor(x1, m);
        float o2 = __shfl_xor(x2, m), o3 = __shfl_xor(x3, m);
        float o4 = __shfl_xor(x4, m), o5 = __shfl_xor(x5, m);
        const bool up = (lane & m) != 0;   // this lane holds the LATER segment
        float A0 = up ? o0 : x0, B0 = up ? x0 : o0;
        float A1 = up ? o1 : x1, B1 = up ? x1 : o1;
        float A2 = up ? o2 : x2, B2 = up ? x2 : o2;
        float A3 = up ? o3 : x3, B3 = up ? x3 : o3;
        float A4 = up ? o4 : x4, B4 = up ? x4 : o4;
        float A5 = up ? o5 : x5, B5 = up ? x5 : o5;
        x5 = A5 + B5 + A3 * B2 + A0 * B4;
        x4 = A4 + B4 + A1 * B2;
        x3 = A3 + B3 + A0 * B1;
        x2 = A2 + B2;
        x1 = A1 + B1;
        x0 = A0 + B0;
    }

    if (lg == 0) {
        float* wp = ws + (((size_t)b * TGROUPS + tg) * F_ + f) * 10;
        if (cg == 0) {
            wp[0] = x0; wp[1] = x1; wp[2] = x2; wp[3] = x4;
        } else {
            wp[4] = x0; wp[5] = x1; wp[6] = x2;
            wp[7] = x3; wp[8] = x4; wp[9] = x5;
        }
    }
}

struct St { float a0, s1, s2, q2, su, sv, sw, qvu, qwv, qwvu; };

__device__ __forceinline__ St mergeSt(const St& A, const St& B) {
    St r;
    r.a0   = A.a0 + B.a0;
    r.q2   = A.q2 + B.q2 + A.s1 * B.s2;
    r.s1   = A.s1 + B.s1;
    r.s2   = A.s2 + B.s2;
    r.qwvu = A.qwvu + B.qwvu + A.qvu * B.sw + A.su * B.qwv;
    r.qwv  = A.qwv + B.qwv + A.sv * B.sw;
    r.qvu  = A.qvu + B.qvu + A.su * B.sv;
    r.su   = A.su + B.su;
    r.sv   = A.sv + B.sv;
    r.sw   = A.sw + B.sw;
    return r;
}

__global__ __launch_bounds__(64)
void ls2t_fold_kernel(const float* __restrict__ ws, float* __restrict__ out)
{
    const int b = blockIdx.x;
    const int f = threadIdx.x;
    St A = {0, 0, 0, 0, 0, 0, 0, 0, 0, 0};
    #pragma unroll
    for (int g = 0; g < TGROUPS; ++g) {
        const float* rp = ws + (((size_t)b * TGROUPS + g) * F_ + f) * 10;
        St r = {rp[0], rp[1], rp[2], rp[3], rp[4],
                rp[5], rp[6], rp[7], rp[8], rp[9]};
        A = mergeSt(A, r);
    }
    float* op = out + ((size_t)b * F_ + f) * 3;
    op[0] = A.a0;
    op[1] = A.q2;
    op[2] = A.qwvu;
}

extern "C" void kernel_launch(void* const* d_in, const int* in_sizes, int n_in,
                              void* d_out, int out_size, void* d_ws, size_t ws_size,
                              hipStream_t stream) {
    const float* seq  = (const float*)d_in[0];
    const float* kern = (const float*)d_in[1];
    const float* bias = (const float*)d_in[2];
    float* out = (float*)d_out;
    float* ws  = (float*)d_ws;   // B_*TGROUPS*F_*10*4 = 1.31 MB

    dim3 g1(TGROUPS, B_);        // 512 blocks x 512 thr -> 3 blocks/CU
    ls2t_kernel<<<g1, TPB, 0, stream>>>(seq, kern, bias, ws);
    ls2t_fold_kernel<<<B_, F_, 0, stream>>>(ws, out);
}

// Round 22
// 41.546 us; speedup vs baseline: 4.2784x; 1.0001x over previous
//
#include <hip/hip_runtime.h>
#include <hip/hip_bf16.h>

// LS2T iterated sums (ORDER=3): B=64, T=4096, D=128, F=64, C=6.
// m_c(t,f) = seq[b,t,:]·kernel[c,:,f] + bias[c,f]
// Y1 = sum m0; Y2 = sum m2*cumx(m1); Y3 = sum m5*cumx(m4*cumx(m3))
//
// Round 22: R15 pipeline + cooperative f32->bf16 LDS conversion stage.
// Per phase: [VW(2); BAR; issue DMA chunk i+2; compute chunk i-1 from bf16;
// convert chunk i f32->bf16]. Compute path: 8 ds_read_b128/wave/chunk
// (was 16) and ZERO v_perms (one b128 = one full K=32 bf16 slice).
// bf16 ring-2 uses 4-bit XOR unit swizzle (bank-optimal). LDS = 3x16KB f32
// + 2x8KB bf16 = 64 KB (R15 footprint). DMA geometry, counted vmcnt,
// cg-split, unified 6-reg scan, butterfly merge, fold kernel: R15 exact.

#define B_ 64
#define T_ 4096
#define D_ 128
#define F_ 64
#define TB 512             // t per block
#define TGROUPS (T_ / TB)  // 8
#define CHT 32             // t per chunk (2 MFMA sub-tiles)
#define NITER (TB / CHT)   // 16
#define TPB 512
#define RINGF 3
#define RINGH 2

typedef __attribute__((ext_vector_type(8))) short short8v;
typedef __attribute__((ext_vector_type(4))) float f32x4;

__device__ __forceinline__ unsigned short bfb(float x) {
    __hip_bfloat16 h = __float2bfloat16(x);   // RNE (B operand only)
    unsigned short u;
    __builtin_memcpy(&u, &h, 2);
    return u;
}

// barrier WITHOUT vmcnt drain: waits only LDS ops, keeps DMAs in flight
#define BAR() asm volatile("s_waitcnt lgkmcnt(0)\n\ts_barrier" ::: "memory")
#define VW(n) asm volatile("s_waitcnt vmcnt(" #n ")" ::: "memory")

__global__ __launch_bounds__(TPB)
void ls2t_kernel(const float* __restrict__ seq,
                 const float* __restrict__ kern,
                 const float* __restrict__ bias,
                 float* __restrict__ ws)
{
    __shared__ float slds[RINGF][CHT * D_];            // 3 x 16 KB f32
    __shared__ unsigned short hlds[RINGH][CHT * D_];   // 2 x 8 KB bf16

    const int tid  = threadIdx.x;
    const int tg   = blockIdx.x;
    const int b    = blockIdx.y;
    const int lane = tid & 63;
    const int w    = tid >> 6;
    const int cg   = w >> 2;       // 0 -> c0..2 (Y1,Y2), 1 -> c3..5 (Y3)
    const int wv   = w & 3;        // f-range of this wave
    const int fr   = lane & 15;
    const int lg   = lane >> 4;
    const int f    = wv * 16 + fr;

    // ---- B fragments in registers (mfma B: col=lane&15=f, k=(lane>>4)*8+j)
    short8v bfrag[3][4];
    float bc[3];
    #pragma unroll
    for (int cc = 0; cc < 3; ++cc) {
        const int c = cg * 3 + cc;
        bc[cc] = bias[c * F_ + f];
        #pragma unroll
        for (int ks = 0; ks < 4; ++ks) {
            const float* kp = kern + ((size_t)c * D_ + ks * 32 + lg * 8) * F_ + f;
            short8v bf;
            #pragma unroll
            for (int j = 0; j < 8; ++j) bf[j] = (short)bfb(kp[(size_t)j * F_]);
            bfrag[cc][ks] = bf;
        }
    }

    const float* sbase = seq + ((size_t)b * T_ + (size_t)tg * TB) * D_;

    // ---- DMA staging geometry (R15 exact) ----
    // Chunk = 32 rows. Row R (0..31) of chunk i holds
    //   t_local = ((R&15)>>2)*128 + ((R>>4)<<2) + (R&3) + i*8
    // (sub-tile tf=R>>4, MFMA row rho=R&15; lane-group lg owns contiguous
    // t-stripe [lg*128,+128) over the 16 chunks). Wave w stages rows
    // {4w..4w+3} via 2 loads; dest linear (base + lane*16B). Pre-swizzled
    // SOURCE: f32 LDS 16B-unit u of row R holds global unit (u&24)|((u^R)&7).
    const int u_lane = lane & 31;
    const float* gsrc0[2];
    #pragma unroll
    for (int j = 0; j < 2; ++j) {
        const int r  = 4 * w + 2 * j + (lane >> 5);
        const int gu = (u_lane & 24) | ((u_lane ^ r) & 7);
        const int t0 = ((r & 15) >> 2) * 128 + ((r >> 4) << 2) + (r & 3);
        gsrc0[j] = sbase + (size_t)t0 * D_ + gu * 4;
    }

    auto issue = [&](int i, int bufi) {
        #pragma unroll
        for (int j = 0; j < 2; ++j) {
            const float* src = gsrc0[j] + (size_t)i * 8 * D_;
            void* dst = (void*)&slds[bufi][(4 * w + 2 * j) * 128];
            __builtin_amdgcn_global_load_lds(
                (const __attribute__((address_space(1))) void*)src,
                (__attribute__((address_space(3))) void*)dst, 16, 0, 0);
        }
    };

    // ---- conversion: f32 chunk -> bf16 chunk, 512 threads cover 32x16 units
    // Thread t: row = t>>4, bf16 unit u = t&15 (u <-> f32 units 2u,2u+1).
    // f32 unit v sits at swizzled pos (v&24)|((v^row)&7); bf16 unit u is
    // written at u^(row&15) (4-bit XOR swizzle, bank-optimal on read).
    auto convert = [&](int fbuf, int hbuf) {
        const int row = tid >> 4;
        const int u   = tid & 15;
        const float* Fp = &slds[fbuf][0];
        const int v0 = 2 * u, v1 = 2 * u + 1;
        const int p0 = (v0 & 24) | ((v0 ^ row) & 7);
        const int p1 = (v1 & 24) | ((v1 ^ row) & 7);
        float4 fa = *reinterpret_cast<const float4*>(&Fp[row * 128 + p0 * 4]);
        float4 fb = *reinterpret_cast<const float4*>(&Fp[row * 128 + p1 * 4]);
        uint4 pk;
        pk.x = __builtin_amdgcn_perm(__float_as_uint(fa.y),
                                     __float_as_uint(fa.x), 0x07060302u);
        pk.y = __builtin_amdgcn_perm(__float_as_uint(fa.w),
                                     __float_as_uint(fa.z), 0x07060302u);
        pk.z = __builtin_amdgcn_perm(__float_as_uint(fb.y),
                                     __float_as_uint(fb.x), 0x07060302u);
        pk.w = __builtin_amdgcn_perm(__float_as_uint(fb.w),
                                     __float_as_uint(fb.z), 0x07060302u);
        *reinterpret_cast<uint4*>(
            &hlds[hbuf][row * 128 + ((u ^ (row & 15)) * 8)]) = pk;
    };

    // unified scan state (cg0: a0=x0,s1=x1,s2=x2,q2=x4; cg1: su..qwvu=x0..x5)
    float x0 = 0.f, x1 = 0.f, x2 = 0.f, x3 = 0.f, x4 = 0.f, x5 = 0.f;

    auto compute = [&](int hbuf) {
        const unsigned short* H = &hlds[hbuf][0];
        #pragma unroll
        for (int tf = 0; tf < 2; ++tf) {       // two 16x16 sub-tiles
            f32x4 acc[3];
            #pragma unroll
            for (int cc = 0; cc < 3; ++cc)
                acc[cc] = (f32x4){bc[cc], bc[cc], bc[cc], bc[cc]};

            const int rowbase = (tf * 16 + fr) * 128;   // shorts
            #pragma unroll
            for (int ks = 0; ks < 4; ++ks) {
                const int u = (ks * 4 + lg) ^ fr;       // row&15 == fr
                short8v a = *reinterpret_cast<const short8v*>(
                    &H[rowbase + u * 8]);
                #pragma unroll
                for (int cc = 0; cc < 3; ++cc)
                    acc[cc] = __builtin_amdgcn_mfma_f32_16x16x32_bf16(
                        a, bfrag[cc][ks], acc[cc], 0, 0, 0);
            }

            // lane owns t = tg*512 + lg*128 + i*8 + tf*4 + r -> chain in-lane
            #pragma unroll
            for (int r = 0; r < 4; ++r) {
                float p = acc[0][r], q = acc[1][r], rr = acc[2][r];
                x5 = fmaf(rr, x3, x5);   // qwvu += m5*qvu            (cg1)
                x4 = fmaf(rr, x1, x4);   // q2 += m2*s1 / qwv += m5*sv
                x3 = fmaf(q,  x0, x3);   // qvu += m4*su              (cg1)
                x2 += rr;                // s2 / sw
                x1 += q;                 // s1 / sv
                x0 += p;                 // a0 / su
            }
        }
    };

    // ---- pipeline: DMA 2 ahead (ring-3 f32), convert(i) || compute(i-1) ----
    issue(0, 0); issue(1, 1);
    int c0 = 0, c1 = 1, c2 = 2;        // f32 bufs of chunks i, i+1, i+2

    // peel i = 0
    VW(2); BAR();                      // chunk 0 landed (chunk 1 in flight)
    issue(2, c2);
    convert(c0, 0);
    { int t = c0; c0 = c1; c1 = c2; c2 = t; }

    #pragma unroll 1
    for (int i = 1; i < NITER - 1; ++i) {
        VW(2);                 // chunk i landed (i+1 in flight)
        BAR();                 // publishes convert(i-1) writes + DMA rows
        if (i + 2 < NITER) issue(i + 2, c2);
        compute((i - 1) & 1);  // from bf16
        convert(c0, i & 1);    // f32 chunk i -> bf16
        int t = c0; c0 = c1; c1 = c2; c2 = t;
    }

    // epilogue: i = 15
    VW(0); BAR();
    compute(0);                // chunk 14 (converted at i=14)
    convert(c0, 1);            // chunk 15
    BAR();                     // publish convert(15)
    compute(1);                // chunk 15

    // ---- merge the 4 lane-group stripes (time order: lg ascending) ----
    #pragma unroll
    for (int m = 16; m <= 32; m <<= 1) {
        float o0 = __shfl_xor(x0, m), o1 = __shfl_xor(x1, m);
        float o2 = __shfl_xor(x2, m), o3 = __shfl_xor(x3, m);
        float o4 = __shfl_xor(x4, m), o5 = __shfl_xor(x5, m);
        const bool up = (lane & m) != 0;   // this lane holds the LATER segment
        float A0 = up ? o0 : x0, B0 = up ? x0 : o0;
        float A1 = up ? o1 : x1, B1 = up ? x1 : o1;
        float A2 = up ? o2 : x2, B2 = up ? x2 : o2;
        float A3 = up ? o3 : x3, B3 = up ? x3 : o3;
        float A4 = up ? o4 : x4, B4 = up ? x4 : o4;
        float A5 = up ? o5 : x5, B5 = up ? x5 : o5;
        x5 = A5 + B5 + A3 * B2 + A0 * B4;
        x4 = A4 + B4 + A1 * B2;
        x3 = A3 + B3 + A0 * B1;
        x2 = A2 + B2;
        x1 = A1 + B1;
        x0 = A0 + B0;
    }

    if (lg == 0) {
        float* wp = ws + (((size_t)b * TGROUPS + tg) * F_ + f) * 10;
        if (cg == 0) {
            wp[0] = x0; wp[1] = x1; wp[2] = x2; wp[3] = x4;
        } else {
            wp[4] = x0; wp[5] = x1; wp[6] = x2;
            wp[7] = x3; wp[8] = x4; wp[9] = x5;
        }
    }
}

struct St { float a0, s1, s2, q2, su, sv, sw, qvu, qwv, qwvu; };

__device__ __forceinline__ St mergeSt(const St& A, const St& B) {
    St r;
    r.a0   = A.a0 + B.a0;
    r.q2   = A.q2 + B.q2 + A.s1 * B.s2;
    r.s1   = A.s1 + B.s1;
    r.s2   = A.s2 + B.s2;
    r.qwvu = A.qwvu + B.qwvu + A.qvu * B.sw + A.su * B.qwv;
    r.qwv  = A.qwv + B.qwv + A.sv * B.sw;
    r.qvu  = A.qvu + B.qvu + A.su * B.sv;
    r.su   = A.su + B.su;
    r.sv   = A.sv + B.sv;
    r.sw   = A.sw + B.sw;
    return r;
}

__global__ __launch_bounds__(64)
void ls2t_fold_kernel(const float* __restrict__ ws, float* __restrict__ out)
{
    const int b = blockIdx.x;
    const int f = threadIdx.x;
    St A = {0, 0, 0, 0, 0, 0, 0, 0, 0, 0};
    #pragma unroll
    for (int g = 0; g < TGROUPS; ++g) {
        const float* rp = ws + (((size_t)b * TGROUPS + g) * F_ + f) * 10;
        St r = {rp[0], rp[1], rp[2], rp[3], rp[4],
                rp[5], rp[6], rp[7], rp[8], rp[9]};
        A = mergeSt(A, r);
    }
    float* op = out + ((size_t)b * F_ + f) * 3;
    op[0] = A.a0;
    op[1] = A.q2;
    op[2] = A.qwvu;
}

extern "C" void kernel_launch(void* const* d_in, const int* in_sizes, int n_in,
                              void* d_out, int out_size, void* d_ws, size_t ws_size,
                              hipStream_t stream) {
    const float* seq  = (const float*)d_in[0];
    const float* kern = (const float*)d_in[1];
    const float* bias = (const float*)d_in[2];
    float* out = (float*)d_out;
    float* ws  = (float*)d_ws;   // B_*TGROUPS*F_*10*4 = 1.31 MB

    dim3 g1(TGROUPS, B_);        // 512 blocks x 512 thr
    ls2t_kernel<<<g1, TPB, 0, stream>>>(seq, kern, bias, ws);
    ls2t_fold_kernel<<<B_, F_, 0, stream>>>(ws, out);
}